// Round 1
// baseline (228.488 us; speedup 1.0000x reference)
//
#include <hip/hip_runtime.h>
#include <math.h>

// Problem constants (B=1, C=256, T=8, H=32, W=32, L=4, NUM_PTS=4, N_OFF=4)
#define CDIM 256
#define TDIM 8
#define HDIM 32
#define WDIM 32
#define LDIM 4
#define THW 8192
#define CSTR 32768            // T*H*W*L, per-channel stride in features
#define NS 64                 // NUM_PTS^3
#define OUT0_SIZE 8388608     // C*T*H*W*L

// uniform_flat_indices axes for T=8 / H=W=32, n=4 (round(linspace(hop/2, D-1-hop/2, 4)))
__device__ __constant__ int c_ti[4] = {1, 3, 4, 6};
__device__ __constant__ int c_hw[4] = {4, 12, 19, 27};

__device__ __forceinline__ float sigm(float x) { return 1.f / (1.f + expf(-x)); }

__device__ __forceinline__ float wave_sum64(float x) {
#pragma unroll
    for (int s = 32; s > 0; s >>= 1) x += __shfl_xor(x, s, 64);
    return x;
}

// ---------------- 1. Fill entire output0 with beta[c] ----------------
__global__ void k_fill(const float* __restrict__ beta, float* __restrict__ out) {
    int c = blockIdx.x;
    float b = beta[c];
    float4 v = make_float4(b, b, b, b);
    float4* o = (float4*)(out + (size_t)c * CSTR);
    for (int i = threadIdx.x; i < CSTR / 4; i += 256) o[i] = v;
}

// ---------------- 2. glob[l*256+c] = mean over THW of features[c,:,:,:,l] ----------------
__global__ void k_glob(const float* __restrict__ feat, float* __restrict__ glob) {
    int c = blockIdx.x;
    const float4* f = (const float4*)(feat + (size_t)c * CSTR);
    float4 a = make_float4(0.f, 0.f, 0.f, 0.f);
    for (int i = threadIdx.x; i < THW; i += 256) {
        float4 v = f[i];
        a.x += v.x; a.y += v.y; a.z += v.z; a.w += v.w;
    }
    __shared__ float4 sred[256];
    sred[threadIdx.x] = a;
    __syncthreads();
    for (int off = 128; off > 0; off >>= 1) {
        if (threadIdx.x < off) {
            float4 b = sred[threadIdx.x + off];
            sred[threadIdx.x].x += b.x; sred[threadIdx.x].y += b.y;
            sred[threadIdx.x].z += b.z; sred[threadIdx.x].w += b.w;
        }
        __syncthreads();
    }
    if (threadIdx.x == 0) {
        float4 t = sred[0];
        glob[0 * CDIM + c] = t.x * (1.f / 8192.f);
        glob[1 * CDIM + c] = t.y * (1.f / 8192.f);
        glob[2 * CDIM + c] = t.z * (1.f / 8192.f);
        glob[3 * CDIM + c] = t.w * (1.f / 8192.f);
    }
}

// ---------------- 3. Build off_src input rows: [pts(256) | pos(256) | glob(256)] ----------------
__global__ void k_gather(const float* __restrict__ feat, const float* __restrict__ pos,
                         const float* __restrict__ glob, float* __restrict__ in1) {
    int m = blockIdx.x;             // m = l*64 + n
    int l = m >> 6, n = m & 63;
    int sp = (c_ti[n >> 4] * HDIM + c_hw[(n >> 2) & 3]) * WDIM + c_hw[n & 3];
    for (int k = threadIdx.x; k < 768; k += 256) {
        float v;
        if (k < 256)      v = feat[(size_t)k * CSTR + sp * LDIM + l];
        else if (k < 512) v = pos[(size_t)(k - 256) * CSTR + sp * LDIM + l];
        else              v = glob[l * CDIM + (k - 512)];
        in1[m * 768 + k] = v;
    }
}

// ---------------- 4/5. GEMM + bias + relu: out[m,j] = relu(in[m,:] @ Wt[:,j] + b[j]) ----------------
template <int K>
__global__ void k_gemm_relu(const float* __restrict__ in, const float* __restrict__ Wt,
                            const float* __restrict__ b, float* __restrict__ out) {
    __shared__ float srow[K];
    int m = blockIdx.x;
    for (int k = threadIdx.x; k < K; k += 256) srow[k] = in[m * K + k];
    __syncthreads();
    int j = threadIdx.x;
    float acc = 0.f;
#pragma unroll 8
    for (int k = 0; k < K; ++k) acc += srow[k] * Wt[k * 256 + j];
    acc += b[j];
    out[m * 256 + j] = fmaxf(acc, 0.f);
}

// ---------------- 6. Heads: nxt->next_ind, per-o offset->samp, w_o ----------------
__global__ void k_heads(const float* __restrict__ osrc,
                        const float* __restrict__ Wn, const float* __restrict__ bn,
                        const float* __restrict__ Woff, const float* __restrict__ boff,
                        const float* __restrict__ Ww, const float* __restrict__ bw,
                        float* __restrict__ samp, float* __restrict__ wo,
                        float* __restrict__ next_out) {
    int m = blockIdx.x;             // l*64 + n
    int l = m >> 6, n = m & 63;
    int j = threadIdx.x;            // 0..63 (one wave)
    float v[4];
#pragma unroll
    for (int o = 0; o < 4; ++o) v[o] = osrc[m * 256 + o * 64 + j];

    // nxt = off_src @ Wn (+bn later)
    float pn0 = 0.f, pn1 = 0.f, pn2 = 0.f;
#pragma unroll
    for (int o = 0; o < 4; ++o) {
        int r = o * 64 + j;
        pn0 += v[o] * Wn[r * 3 + 0];
        pn1 += v[o] * Wn[r * 3 + 1];
        pn2 += v[o] * Wn[r * 3 + 2];
    }
    pn0 = wave_sum64(pn0); pn1 = wave_sum64(pn1); pn2 = wave_sum64(pn2);

    float tn = (float)c_ti[n >> 4] / 7.f;
    float hn = (float)c_hw[(n >> 2) & 3] / 31.f;
    float wn = (float)c_hw[n & 3] / 31.f;
    float lg0 = logf(tn / (1.f - tn));
    float lg1 = logf(hn / (1.f - hn));
    float lg2 = logf(wn / (1.f - wn));

#pragma unroll
    for (int o = 0; o < 4; ++o) {
        float po0 = wave_sum64(v[o] * Woff[j * 3 + 0]);
        float po1 = wave_sum64(v[o] * Woff[j * 3 + 1]);
        float po2 = wave_sum64(v[o] * Woff[j * 3 + 2]);
        float z0  = wave_sum64(v[o] * Ww[j * 2 + 0]);
        float z1  = wave_sum64(v[o] * Ww[j * 2 + 1]);
        if (j == 0) {
            int q = l * 4 + o;
            samp[(q * NS + n) * 3 + 0] = sigm(lg0 + po0 + boff[0]) * 2.f - 1.f;
            samp[(q * NS + n) * 3 + 1] = sigm(lg1 + po1 + boff[1]) * 2.f - 1.f;
            samp[(q * NS + n) * 3 + 2] = sigm(lg2 + po2 + boff[2]) * 2.f - 1.f;
            // softmax([z0,z1])[1] = sigmoid(z1-z0)
            wo[q * NS + n] = 1.f / (1.f + expf((z0 + bw[0]) - (z1 + bw[1])));
        }
    }
    if (j == 0) {
        float d0 = rintf(sigm(lg0 + pn0 + bn[0]) * 7.f);
        float d1 = rintf(sigm(lg1 + pn1 + bn[1]) * 31.f);
        float d2 = rintf(sigm(lg2 + pn2 + bn[2]) * 31.f);
        next_out[m] = 1024.f * d0 + 32.f * d1 + d2;   // H*W*d0 + W*d1 + d2
    }
}

// ---------------- 7. Trilinear sample at the 64 sites + LayerNorm + scatter-write ----------------
__global__ void k_sample_ln(const float* __restrict__ feat,
                            const float* __restrict__ samp, const float* __restrict__ wo,
                            const float* __restrict__ gamma, const float* __restrict__ beta,
                            float* __restrict__ out) {
    __shared__ float s_w[32];
    __shared__ int s_o[32];
    __shared__ float red1[4], red2[4];
    int bm = blockIdx.x;            // l*64 + n
    int l = bm >> 6, n = bm & 63;
    int tid = threadIdx.x;

    if (tid < 4) {
        int o = tid, q = l * 4 + o;
        float wv = wo[q * NS + n];
        float g0 = samp[(q * NS + n) * 3 + 0];
        float g1 = samp[(q * NS + n) * 3 + 1];
        float g2 = samp[(q * NS + n) * 3 + 2];
        // reference grid_sample: ch0 -> x over W, ch1 -> y over H, ch2 -> z over D(=T)
        float ix = ((g0 + 1.f) * 32.f - 1.f) * 0.5f;
        float iy = ((g1 + 1.f) * 32.f - 1.f) * 0.5f;
        float iz = ((g2 + 1.f) * 8.f  - 1.f) * 0.5f;
        float x0f = floorf(ix), y0f = floorf(iy), z0f = floorf(iz);
        float fx = ix - x0f, fy = iy - y0f, fz = iz - z0f;
        int x0 = (int)x0f, y0 = (int)y0f, z0 = (int)z0f;
#pragma unroll
        for (int k = 0; k < 8; ++k) {
            int dx = k & 1, dy = (k >> 1) & 1, dz = k >> 2;
            int xi = x0 + dx, yi = y0 + dy, zi = z0 + dz;
            float w = (dx ? fx : 1.f - fx) * (dy ? fy : 1.f - fy) * (dz ? fz : 1.f - fz);
            bool valid = (xi >= 0) && (xi < WDIM) && (yi >= 0) && (yi < HDIM) && (zi >= 0) && (zi < TDIM);
            int xc = min(max(xi, 0), WDIM - 1);
            int yc = min(max(yi, 0), HDIM - 1);
            int zc = min(max(zi, 0), TDIM - 1);
            s_w[o * 8 + k] = valid ? w * wv : 0.f;
            s_o[o * 8 + k] = ((zc * HDIM + yc) * WDIM + xc) * LDIM + l;
        }
    }
    __syncthreads();

    int c = tid;
    const float* fc = feat + (size_t)c * CSTR;
    int sp = (c_ti[n >> 4] * HDIM + c_hw[(n >> 2) & 3]) * WDIM + c_hw[n & 3];
    float acc = fc[sp * LDIM + l];          // features + wsf at this site
#pragma unroll
    for (int k = 0; k < 32; ++k) acc += s_w[k] * fc[s_o[k]];

    // LayerNorm over C=256 (one value per thread)
    float s1 = acc, s2 = acc * acc;
#pragma unroll
    for (int d = 32; d > 0; d >>= 1) { s1 += __shfl_xor(s1, d, 64); s2 += __shfl_xor(s2, d, 64); }
    int wid = tid >> 6;
    if ((tid & 63) == 0) { red1[wid] = s1; red2[wid] = s2; }
    __syncthreads();
    float tot  = red1[0] + red1[1] + red1[2] + red1[3];
    float totq = red2[0] + red2[1] + red2[2] + red2[3];
    float mu = tot * (1.f / 256.f);
    float var = fmaxf(totq * (1.f / 256.f) - mu * mu, 0.f);
    float y = (acc - mu) * rsqrtf(var + 1e-5f) * gamma[c] + beta[c];
    out[(size_t)c * CSTR + sp * LDIM + l] = y;
}

extern "C" void kernel_launch(void* const* d_in, const int* in_sizes, int n_in,
                              void* d_out, int out_size, void* d_ws, size_t ws_size,
                              hipStream_t stream) {
    const float* feat = (const float*)d_in[0];
    const float* pos  = (const float*)d_in[1];
    const float* W1   = (const float*)d_in[2];
    const float* b1   = (const float*)d_in[3];
    const float* W2   = (const float*)d_in[4];
    const float* b2   = (const float*)d_in[5];
    const float* Wn   = (const float*)d_in[6];
    const float* bn   = (const float*)d_in[7];
    // d_in[8]=Wl, d_in[9]=bl are provably unused (softmax rows sum to 1)
    const float* Woff = (const float*)d_in[10];
    const float* boff = (const float*)d_in[11];
    const float* Ww   = (const float*)d_in[12];
    const float* bw   = (const float*)d_in[13];
    const float* gamma= (const float*)d_in[14];
    const float* beta = (const float*)d_in[15];
    float* out = (float*)d_out;

    float* ws   = (float*)d_ws;
    float* glob = ws;               // 1024
    float* in1  = ws + 1024;        // 196608
    float* h1   = ws + 197632;      // 65536
    float* osrc = ws + 263168;      // 65536
    float* samp = ws + 328704;      // 3072
    float* wov  = ws + 331776;      // 1024

    k_fill<<<256, 256, 0, stream>>>(beta, out);
    k_glob<<<256, 256, 0, stream>>>(feat, glob);
    k_gather<<<256, 256, 0, stream>>>(feat, pos, glob, in1);
    k_gemm_relu<768><<<256, 256, 0, stream>>>(in1, W1, b1, h1);
    k_gemm_relu<256><<<256, 256, 0, stream>>>(h1, W2, b2, osrc);
    k_heads<<<256, 64, 0, stream>>>(osrc, Wn, bn, Woff, boff, Ww, bw, samp, wov, out + OUT0_SIZE);
    k_sample_ln<<<256, 256, 0, stream>>>(feat, samp, wov, gamma, beta, out);
}

// Round 2
// 177.926 us; speedup vs baseline: 1.2842x; 1.2842x over previous
//
#include <hip/hip_runtime.h>
#include <math.h>

// Problem constants (B=1, C=256, T=8, H=32, W=32, L=4, NUM_PTS=4, N_OFF=4)
#define CDIM 256
#define TDIM 8
#define HDIM 32
#define WDIM 32
#define LDIM 4
#define THW 8192
#define CSTR 32768            // T*H*W*L, per-channel stride in features
#define NS 64                 // NUM_PTS^3
#define OUT0_SIZE 8388608     // C*T*H*W*L

#define K1 768
#define NS1 16                // k-splits for GEMM1
#define KB1 48                // 768/16
#define K2 256
#define NS2 16                // k-splits for GEMM2
#define KB2 16                // 256/16

// uniform_flat_indices axes for T=8 / H=W=32, n=4 (round(linspace(hop/2, D-1-hop/2, 4)))
__device__ __constant__ int c_ti[4] = {1, 3, 4, 6};
__device__ __constant__ int c_hw[4] = {4, 12, 19, 27};

__device__ __forceinline__ float sigm(float x) { return 1.f / (1.f + expf(-x)); }

__device__ __forceinline__ float wave_sum64(float x) {
#pragma unroll
    for (int s = 32; s > 0; s >>= 1) x += __shfl_xor(x, s, 64);
    return x;
}

// ---------------- 1. Fill output0 with beta[c] AND compute glob in one pass ----------------
__global__ void k_fill_glob(const float* __restrict__ feat, const float* __restrict__ beta,
                            float* __restrict__ out, float* __restrict__ glob) {
    int c = blockIdx.x;
    float b = beta[c];
    float4 bv = make_float4(b, b, b, b);
    const float4* f = (const float4*)(feat + (size_t)c * CSTR);
    float4* o = (float4*)(out + (size_t)c * CSTR);
    float4 a = make_float4(0.f, 0.f, 0.f, 0.f);
    for (int i = threadIdx.x; i < THW; i += 256) {
        float4 v = f[i];
        o[i] = bv;
        a.x += v.x; a.y += v.y; a.z += v.z; a.w += v.w;
    }
    __shared__ float4 sred[256];
    sred[threadIdx.x] = a;
    __syncthreads();
    for (int off = 128; off > 0; off >>= 1) {
        if (threadIdx.x < off) {
            float4 t = sred[threadIdx.x + off];
            sred[threadIdx.x].x += t.x; sred[threadIdx.x].y += t.y;
            sred[threadIdx.x].z += t.z; sred[threadIdx.x].w += t.w;
        }
        __syncthreads();
    }
    if (threadIdx.x == 0) {
        float4 t = sred[0];
        glob[0 * CDIM + c] = t.x * (1.f / 8192.f);
        glob[1 * CDIM + c] = t.y * (1.f / 8192.f);
        glob[2 * CDIM + c] = t.z * (1.f / 8192.f);
        glob[3 * CDIM + c] = t.w * (1.f / 8192.f);
    }
}

// ---------------- 2. Build off_src input rows: [pts(256) | pos(256) | glob(256)] ----------------
__global__ void k_gather(const float* __restrict__ feat, const float* __restrict__ pos,
                         const float* __restrict__ glob, float* __restrict__ in1) {
    int m = blockIdx.x;             // m = l*64 + n
    int l = m >> 6, n = m & 63;
    int sp = (c_ti[n >> 4] * HDIM + c_hw[(n >> 2) & 3]) * WDIM + c_hw[n & 3];
    for (int k = threadIdx.x; k < 768; k += 256) {
        float v;
        if (k < 256)      v = feat[(size_t)k * CSTR + sp * LDIM + l];
        else if (k < 512) v = pos[(size_t)(k - 256) * CSTR + sp * LDIM + l];
        else              v = glob[l * CDIM + (k - 512)];
        in1[m * 768 + k] = v;
    }
}

// ---------------- 3/5. Split-K partial GEMM: part[ks][m][j] = sum_{k in chunk} A[m][k]*Wt[k][j] ----
// A is read with block-uniform indices -> scalar loads; thread j streams W column j (coalesced).
template <int K, int KB, int NKS>
__global__ void k_gemm_part(const float* __restrict__ A, const float* __restrict__ Wt,
                            float* __restrict__ part) {
    int mt = blockIdx.x / NKS, ks = blockIdx.x % NKS;
    int j = threadIdx.x;
    int m0 = mt * 16;
    const float* __restrict__ Arow = A + (size_t)m0 * K + ks * KB;
    const float* __restrict__ Wp = Wt + (size_t)(ks * KB) * 256 + j;
    float acc[16];
#pragma unroll
    for (int i = 0; i < 16; ++i) acc[i] = 0.f;
#pragma unroll 4
    for (int kk = 0; kk < KB; ++kk) {
        float wv = Wp[kk * 256];
#pragma unroll
        for (int i = 0; i < 16; ++i)
            acc[i] = fmaf(Arow[i * K + kk], wv, acc[i]);
    }
#pragma unroll
    for (int i = 0; i < 16; ++i)
        part[((size_t)(ks * 256 + m0 + i)) * 256 + j] = acc[i];
}

// ---------------- 4. Reduce GEMM1 partials -> h1 = relu(sum + b1) ----------------
__global__ void k_h1red(const float* __restrict__ p1, const float* __restrict__ b1,
                        float* __restrict__ h1) {
    int m = blockIdx.x, k = threadIdx.x;
    float v = b1[k];
#pragma unroll
    for (int s = 0; s < NS1; ++s) v += p1[((size_t)(s * 256 + m)) * 256 + k];
    h1[m * 256 + k] = fmaxf(v, 0.f);
}

// ---------------- 6. Heads: reduce GEMM2 partials -> osrc, then all head projections ----------------
__global__ void k_heads(const float* __restrict__ p2, const float* __restrict__ b2,
                        const float* __restrict__ Wn, const float* __restrict__ bn,
                        const float* __restrict__ Woff, const float* __restrict__ boff,
                        const float* __restrict__ Ww, const float* __restrict__ bw,
                        float* __restrict__ samp, float* __restrict__ wo,
                        float* __restrict__ next_out) {
    __shared__ float redn[3][4];
    int m = blockIdx.x;             // l*64 + n
    int l = m >> 6, n = m & 63;
    int j = threadIdx.x;            // 0..255
    int o = j >> 6;                 // wave index == N_OFF group
    int r = j & 63;

    float v = b2[j];
#pragma unroll
    for (int s = 0; s < NS2; ++s) v += p2[((size_t)(s * 256 + m)) * 256 + j];
    v = fmaxf(v, 0.f);              // osrc[m][j]

    // nxt = osrc @ Wn : full-256 reduction
    float pn0 = wave_sum64(v * Wn[j * 3 + 0]);
    float pn1 = wave_sum64(v * Wn[j * 3 + 1]);
    float pn2 = wave_sum64(v * Wn[j * 3 + 2]);
    if (r == 0) { redn[0][o] = pn0; redn[1][o] = pn1; redn[2][o] = pn2; }

    // per-o heads: offset (Woff: d=64 rows) and w_o (Ww)
    float po0 = wave_sum64(v * Woff[r * 3 + 0]);
    float po1 = wave_sum64(v * Woff[r * 3 + 1]);
    float po2 = wave_sum64(v * Woff[r * 3 + 2]);
    float z0  = wave_sum64(v * Ww[r * 2 + 0]);
    float z1  = wave_sum64(v * Ww[r * 2 + 1]);

    float tn = (float)c_ti[n >> 4] / 7.f;
    float hn = (float)c_hw[(n >> 2) & 3] / 31.f;
    float wn = (float)c_hw[n & 3] / 31.f;
    float lg0 = logf(tn / (1.f - tn));
    float lg1 = logf(hn / (1.f - hn));
    float lg2 = logf(wn / (1.f - wn));

    if (r == 0) {
        int q = l * 4 + o;
        samp[(q * NS + n) * 3 + 0] = sigm(lg0 + po0 + boff[0]) * 2.f - 1.f;
        samp[(q * NS + n) * 3 + 1] = sigm(lg1 + po1 + boff[1]) * 2.f - 1.f;
        samp[(q * NS + n) * 3 + 2] = sigm(lg2 + po2 + boff[2]) * 2.f - 1.f;
        wo[q * NS + n] = 1.f / (1.f + expf((z0 + bw[0]) - (z1 + bw[1])));
    }
    __syncthreads();
    if (j == 0) {
        float t0 = redn[0][0] + redn[0][1] + redn[0][2] + redn[0][3];
        float t1 = redn[1][0] + redn[1][1] + redn[1][2] + redn[1][3];
        float t2 = redn[2][0] + redn[2][1] + redn[2][2] + redn[2][3];
        float d0 = rintf(sigm(lg0 + t0 + bn[0]) * 7.f);
        float d1 = rintf(sigm(lg1 + t1 + bn[1]) * 31.f);
        float d2 = rintf(sigm(lg2 + t2 + bn[2]) * 31.f);
        next_out[m] = 1024.f * d0 + 32.f * d1 + d2;   // H*W*d0 + W*d1 + d2
    }
}

// ---------------- 7. Trilinear sample at the 64 sites + LayerNorm + scatter-write ----------------
__global__ void k_sample_ln(const float* __restrict__ feat,
                            const float* __restrict__ samp, const float* __restrict__ wo,
                            const float* __restrict__ gamma, const float* __restrict__ beta,
                            float* __restrict__ out) {
    __shared__ float s_w[32];
    __shared__ int s_o[32];
    __shared__ float red1[4], red2[4];
    int bm = blockIdx.x;            // l*64 + n
    int l = bm >> 6, n = bm & 63;
    int tid = threadIdx.x;

    if (tid < 4) {
        int o = tid, q = l * 4 + o;
        float wv = wo[q * NS + n];
        float g0 = samp[(q * NS + n) * 3 + 0];
        float g1 = samp[(q * NS + n) * 3 + 1];
        float g2 = samp[(q * NS + n) * 3 + 2];
        float ix = ((g0 + 1.f) * 32.f - 1.f) * 0.5f;
        float iy = ((g1 + 1.f) * 32.f - 1.f) * 0.5f;
        float iz = ((g2 + 1.f) * 8.f  - 1.f) * 0.5f;
        float x0f = floorf(ix), y0f = floorf(iy), z0f = floorf(iz);
        float fx = ix - x0f, fy = iy - y0f, fz = iz - z0f;
        int x0 = (int)x0f, y0 = (int)y0f, z0 = (int)z0f;
#pragma unroll
        for (int k = 0; k < 8; ++k) {
            int dx = k & 1, dy = (k >> 1) & 1, dz = k >> 2;
            int xi = x0 + dx, yi = y0 + dy, zi = z0 + dz;
            float w = (dx ? fx : 1.f - fx) * (dy ? fy : 1.f - fy) * (dz ? fz : 1.f - fz);
            bool valid = (xi >= 0) && (xi < WDIM) && (yi >= 0) && (yi < HDIM) && (zi >= 0) && (zi < TDIM);
            int xc = min(max(xi, 0), WDIM - 1);
            int yc = min(max(yi, 0), HDIM - 1);
            int zc = min(max(zi, 0), TDIM - 1);
            s_w[o * 8 + k] = valid ? w * wv : 0.f;
            s_o[o * 8 + k] = ((zc * HDIM + yc) * WDIM + xc) * LDIM + l;
        }
    }
    __syncthreads();

    int c = tid;
    const float* fc = feat + (size_t)c * CSTR;
    int sp = (c_ti[n >> 4] * HDIM + c_hw[(n >> 2) & 3]) * WDIM + c_hw[n & 3];
    float acc = fc[sp * LDIM + l];
#pragma unroll
    for (int k = 0; k < 32; ++k) acc += s_w[k] * fc[s_o[k]];

    float s1 = acc, s2 = acc * acc;
#pragma unroll
    for (int d = 32; d > 0; d >>= 1) { s1 += __shfl_xor(s1, d, 64); s2 += __shfl_xor(s2, d, 64); }
    int wid = tid >> 6;
    if ((tid & 63) == 0) { red1[wid] = s1; red2[wid] = s2; }
    __syncthreads();
    float tot  = red1[0] + red1[1] + red1[2] + red1[3];
    float totq = red2[0] + red2[1] + red2[2] + red2[3];
    float mu = tot * (1.f / 256.f);
    float var = fmaxf(totq * (1.f / 256.f) - mu * mu, 0.f);
    float y = (acc - mu) * rsqrtf(var + 1e-5f) * gamma[c] + beta[c];
    out[(size_t)c * CSTR + sp * LDIM + l] = y;
}

extern "C" void kernel_launch(void* const* d_in, const int* in_sizes, int n_in,
                              void* d_out, int out_size, void* d_ws, size_t ws_size,
                              hipStream_t stream) {
    const float* feat = (const float*)d_in[0];
    const float* pos  = (const float*)d_in[1];
    const float* W1   = (const float*)d_in[2];
    const float* b1   = (const float*)d_in[3];
    const float* W2   = (const float*)d_in[4];
    const float* b2   = (const float*)d_in[5];
    const float* Wn   = (const float*)d_in[6];
    const float* bn   = (const float*)d_in[7];
    // d_in[8]=Wl, d_in[9]=bl provably unused (softmax rows sum to 1)
    const float* Woff = (const float*)d_in[10];
    const float* boff = (const float*)d_in[11];
    const float* Ww   = (const float*)d_in[12];
    const float* bw   = (const float*)d_in[13];
    const float* gamma= (const float*)d_in[14];
    const float* beta = (const float*)d_in[15];
    float* out = (float*)d_out;

    float* ws   = (float*)d_ws;
    float* glob = ws;                       // 1024
    float* in1  = glob + 1024;              // 196608
    float* p1   = in1 + 196608;             // NS1*256*256 = 1048576
    float* h1   = p1 + (NS1 * 65536);       // 65536
    float* p2   = h1 + 65536;               // NS2*256*256 = 1048576
    float* samp = p2 + (NS2 * 65536);       // 3072
    float* wov  = samp + 3072;              // 1024

    k_fill_glob<<<256, 256, 0, stream>>>(feat, beta, out, glob);
    k_gather<<<256, 256, 0, stream>>>(feat, pos, glob, in1);
    k_gemm_part<K1, KB1, NS1><<<16 * NS1, 256, 0, stream>>>(in1, W1, p1);
    k_h1red<<<256, 256, 0, stream>>>(p1, b1, h1);
    k_gemm_part<K2, KB2, NS2><<<16 * NS2, 256, 0, stream>>>(h1, W2, p2);
    k_heads<<<256, 256, 0, stream>>>(p2, b2, Wn, bn, Woff, boff, Ww, bw, samp, wov, out + OUT0_SIZE);
    k_sample_ln<<<256, 256, 0, stream>>>(feat, samp, wov, gamma, beta, out);
}